// Round 5
// baseline (268.038 us; speedup 1.0000x reference)
//
#include <hip/hip_runtime.h>

// QLoRA NF4 forward: out[b,s,o] = 4.0 * sum_r (sum_i x[b,s,i]*W_A[r,i]) * W_B[o,r]
// B=4 S=2048 IN=4096 OUT=4096 R=8. All fp32.
//
// R8: occupancy + MLP. R7 post-mortem: wA-dedup was worth only 3us; kernel
//  is latency-bound (VALUBusy 18%, BW 2.2TB/s) AND grid-limited on occupancy
//  (1024 blocks = 4 blocks/CU x 4 waves = 16 waves/CU ceiling; measured 37.8%).
//  Fix:
//   - 4 rows/block -> 2048 blocks = 8 blocks/CU -> up to 32 waves/CU offered;
//     cross-block phase overlap (phase-1 streams hide under phase-2 compute).
//   - phase 1: wave owns i-quarter, lane-group owns ONE row (acc[8], fewer
//     regs); unroll 4 -> 4 x-loads in flight per wave (was 2).
//   - wA still read once per block (i-split) -- at 8 blocks/CU the 4x
//     redundant variant would push ~4MiB/CU through L1 and become the wall.
//   - phase 2: proven SGPR-resident interm (readfirstlane), m=4 rows,
//     wBt read once per block, coalesced float4 stores. No launch_bounds
//     floor (R5 lesson: never cap VGPRs below the body's need).
//  Tripwire: WRITE_SIZE must stay exactly 131072 KB.

static __device__ __constant__ float NF4_TBL[16] = {
    -1.0f, -0.6961928009986877f, -0.5250730514526367f, -0.39491748809814453f,
    -0.28444138169288635f, -0.18477343022823334f, -0.09105003625154495f, 0.0f,
    0.07958029955625534f, 0.16093020141124725f, 0.24611230194568634f,
    0.33791524171829224f, 0.44070982933044434f, 0.5626170039176941f,
    0.7229568362236328f, 1.0f};

__global__ void nf4_dequant_kernel(const int* __restrict__ codesA,
                                   const float* __restrict__ absA,
                                   const int* __restrict__ codesB,
                                   const float* __restrict__ absB,
                                   float* __restrict__ wA,    // [8][4096]
                                   float* __restrict__ wBt,   // [8][4096] transposed
                                   int n) {
    int id = blockIdx.x * blockDim.x + threadIdx.x;
    if (id < n) {
        wA[id] = NF4_TBL[codesA[id] & 15] * absA[id >> 6];
        // wBt output-linear: id = r*4096 + o. codes_B flat index = o*8 + r,
        // absmax_B index = (o*8+r)>>6 = o>>3 (r<8). Stores coalesced.
        const int r = id >> 12;
        const int o = id & 4095;
        wBt[id] = NF4_TBL[codesB[o * 8 + r] & 15] * absB[o >> 3];
    }
}

// Fused lora_a + lora_b. Block = 4 rows, 256 threads (4 waves), 2048 blocks
// (8 blocks/CU -> 32 waves/CU offered; latency hiding via TLP).
__global__ __launch_bounds__(256) void lora_fused_kernel(
    const float* __restrict__ x,       // [8192][4096]
    const float* __restrict__ wA,      // [8][4096]
    const float* __restrict__ wBt,     // [8][4096]
    float* __restrict__ out) {         // [8192][4096]
    __shared__ float p_s[4][4][8];     // [wave][row][r] partials
    __shared__ float im_s[4][8];       // combined interm

    const int t    = threadIdx.x;
    const int wave = t >> 6;
    const int lane = t & 63;
    const int g    = lane >> 4;        // lane-group: owns row g
    const int l16  = lane & 15;
    const int row0 = blockIdx.x * 4;

    // ------- phase 1: interm = x @ wA^T ------------------------------------
    // wave owns i-quarter [wave*1024, +1024) = 256 float4; group g owns row g.
    const float4* __restrict__ xg =
        (const float4*)(x + (size_t)(row0 + g) * 4096) + wave * 256;
    const float4* __restrict__ wq = (const float4*)wA + wave * 256;

    float acc[8];
    #pragma unroll
    for (int r = 0; r < 8; ++r) acc[r] = 0.f;

    #pragma unroll 4
    for (int s = 0; s < 16; ++s) {
        const int idx = s * 16 + l16;                   // 256B-coalesced/group
        const float4 xa = xg[idx];
        #pragma unroll
        for (int r = 0; r < 8; ++r) {
            const float4 w = wq[r * 1024 + idx];        // broadcast x4 groups
            acc[r] += xa.x * w.x + xa.y * w.y + xa.z * w.z + xa.w * w.w;
        }
    }

    // reduce across the 16 lanes of each group
    #pragma unroll
    for (int r = 0; r < 8; ++r) {
        float v = acc[r];
        #pragma unroll
        for (int off = 8; off > 0; off >>= 1) v += __shfl_down(v, off, 16);
        if (l16 == 0) p_s[wave][g][r] = v;
    }
    __syncthreads();

    if (t < 32) {                                       // combine 4 quarters
        const int m = t >> 3, r = t & 7;
        im_s[m][r] = (p_s[0][m][r] + p_s[1][m][r] +
                      p_s[2][m][r] + p_s[3][m][r]) * 4.0f;   // SCALING folded
    }
    __syncthreads();

    // ------- phase 2: out = interm @ wBt ----------------------------------
    // interm thread-invariant -> SGPRs via readfirstlane (proven no-spill).
    float ims[4][8];
    #pragma unroll
    for (int m = 0; m < 4; ++m)
        #pragma unroll
        for (int r = 0; r < 8; ++r)
            ims[m][r] = __int_as_float(
                __builtin_amdgcn_readfirstlane(__float_as_int(im_s[m][r])));

    const float4* __restrict__ wt = (const float4*)wBt;   // [8][1024]

    #pragma unroll 1
    for (int k = 0; k < 4; ++k) {
        const int og = t + 256 * k;                       // float4 col group
        float4 w[8];
        #pragma unroll
        for (int r = 0; r < 8; ++r) w[r] = wt[r * 1024 + og];  // coalesced

        #pragma unroll
        for (int m = 0; m < 4; ++m) {
            float4 s;
            s.x = ims[m][0] * w[0].x + ims[m][1] * w[1].x + ims[m][2] * w[2].x
                + ims[m][3] * w[3].x + ims[m][4] * w[4].x + ims[m][5] * w[5].x
                + ims[m][6] * w[6].x + ims[m][7] * w[7].x;
            s.y = ims[m][0] * w[0].y + ims[m][1] * w[1].y + ims[m][2] * w[2].y
                + ims[m][3] * w[3].y + ims[m][4] * w[4].y + ims[m][5] * w[5].y
                + ims[m][6] * w[6].y + ims[m][7] * w[7].y;
            s.z = ims[m][0] * w[0].z + ims[m][1] * w[1].z + ims[m][2] * w[2].z
                + ims[m][3] * w[3].z + ims[m][4] * w[4].z + ims[m][5] * w[5].z
                + ims[m][6] * w[6].z + ims[m][7] * w[7].z;
            s.w = ims[m][0] * w[0].w + ims[m][1] * w[1].w + ims[m][2] * w[2].w
                + ims[m][3] * w[3].w + ims[m][4] * w[4].w + ims[m][5] * w[5].w
                + ims[m][6] * w[6].w + ims[m][7] * w[7].w;
            ((float4*)(out + (size_t)(row0 + m) * 4096))[og] = s;  // coalesced
        }
    }
}

extern "C" void kernel_launch(void* const* d_in, const int* in_sizes, int n_in,
                              void* d_out, int out_size, void* d_ws, size_t ws_size,
                              hipStream_t stream) {
    const float* x        = (const float*)d_in[0];
    const int*   codes_A  = (const int*)d_in[1];
    const float* absmax_A = (const float*)d_in[2];
    const int*   codes_B  = (const int*)d_in[3];
    const float* absmax_B = (const float*)d_in[4];
    float* out = (float*)d_out;

    constexpr int NW = 8 * 4096;                 // elements per factor
    float* wA  = (float*)d_ws;                   // 128 KB
    float* wBt = (float*)d_ws + NW;              // 128 KB (transposed)

    nf4_dequant_kernel<<<(NW + 255) / 256, 256, 0, stream>>>(
        codes_A, absmax_A, codes_B, absmax_B, wA, wBt, NW);

    lora_fused_kernel<<<8192 / 4, 256, 0, stream>>>(x, wA, wBt, out);
}

// Round 6
// 250.292 us; speedup vs baseline: 1.0709x; 1.0709x over previous
//
#include <hip/hip_runtime.h>

// QLoRA NF4 forward: out[b,s,o] = 4.0 * sum_r (sum_i x[b,s,i]*W_A[r,i]) * W_B[o,r]
// B=4 S=2048 IN=4096 OUT=4096 R=8. All fp32.
//
// R9: BARRIER-FREE. R6-R8 post-mortem: VALUBusy pinned ~17%, BW ~2.2TB/s
//  (3x the HBM floor), WRITE clean -> latency-bound with shallow per-wave
//  load depth; the 2-phase + __syncthreads structure collapses the memory
//  pipeline 2x per block and keeps only 2-4 x-loads in flight per wave.
//  Fix: one wave owns 4 complete rows end-to-end. No LDS. No syncthreads.
//   - phase 1: per q-iter, 12 independent float4 loads (4 x-streams + 8 wA)
//     -> ~12-deep vmcnt pipeline per wave, 8 waves/CU => ~96 outstanding
//     loads/CU (Little's law needs ~9 at HBM latency).
//   - wave-reduce acc[4][8] (shfl width 64), ims -> SGPRs via readfirstlane
//     (proven no-spill, v_fma takes SGPR operand free).
//   - phase 2: 16 og-groups; 8 coalesced wBt float4 loads reused across the
//     4 rows; coalesced float4 stores. wA+wBt L2 traffic = 512 MiB total
//     (~11 TB/s, well under the 34.5 TB/s L2 ceiling).
//  Grid: 512 blocks x 256 thr = 2048 waves x 4 rows = 8192 rows. 2 blocks/CU
//  exactly, uniform work, no tail.
//  Tripwire: WRITE_SIZE must stay exactly 131072 KB.

static __device__ __constant__ float NF4_TBL[16] = {
    -1.0f, -0.6961928009986877f, -0.5250730514526367f, -0.39491748809814453f,
    -0.28444138169288635f, -0.18477343022823334f, -0.09105003625154495f, 0.0f,
    0.07958029955625534f, 0.16093020141124725f, 0.24611230194568634f,
    0.33791524171829224f, 0.44070982933044434f, 0.5626170039176941f,
    0.7229568362236328f, 1.0f};

__global__ void nf4_dequant_kernel(const int* __restrict__ codesA,
                                   const float* __restrict__ absA,
                                   const int* __restrict__ codesB,
                                   const float* __restrict__ absB,
                                   float* __restrict__ wA,    // [8][4096]
                                   float* __restrict__ wBt,   // [8][4096] transposed
                                   int n) {
    int id = blockIdx.x * blockDim.x + threadIdx.x;
    if (id < n) {
        wA[id] = NF4_TBL[codesA[id] & 15] * absA[id >> 6];
        // wBt output-linear: id = r*4096 + o. codes_B flat index = o*8 + r,
        // absmax_B index = (o*8+r)>>6 = o>>3 (r<8). Stores coalesced.
        const int r = id >> 12;
        const int o = id & 4095;
        wBt[id] = NF4_TBL[codesB[o * 8 + r] & 15] * absB[o >> 3];
    }
}

// Fused lora. Wave owns 4 rows end-to-end; zero barriers, zero LDS.
__global__ __launch_bounds__(256) void lora_fused_kernel(
    const float* __restrict__ x,       // [8192][4096]
    const float* __restrict__ wA,      // [8][4096]
    const float* __restrict__ wBt,     // [8][4096]
    float* __restrict__ out) {         // [8192][4096]
    const int lane = threadIdx.x & 63;
    const int wid  = blockIdx.x * 4 + (threadIdx.x >> 6);   // 0..2047
    const size_t row0 = (size_t)wid * 4;

    // ------- phase 1: acc[m][r] = partial dot over this lane's i-slice ---
    const float4* __restrict__ x0  = (const float4*)(x + row0 * 4096);
    const float4* __restrict__ x1  = x0 + 1024;
    const float4* __restrict__ x2  = x0 + 2048;
    const float4* __restrict__ x3  = x0 + 3072;
    const float4* __restrict__ wA4 = (const float4*)wA;

    float acc[4][8];
    #pragma unroll
    for (int m = 0; m < 4; ++m)
        #pragma unroll
        for (int r = 0; r < 8; ++r) acc[m][r] = 0.f;

    #pragma unroll 1
    for (int q = 0; q < 16; ++q) {
        const int idx = q * 64 + lane;            // coalesced, 12 loads/iter
        const float4 a0 = x0[idx];
        const float4 a1 = x1[idx];
        const float4 a2 = x2[idx];
        const float4 a3 = x3[idx];
        #pragma unroll
        for (int r = 0; r < 8; ++r) {
            const float4 w = wA4[r * 1024 + idx];
            acc[0][r] += a0.x * w.x + a0.y * w.y + a0.z * w.z + a0.w * w.w;
            acc[1][r] += a1.x * w.x + a1.y * w.y + a1.z * w.z + a1.w * w.w;
            acc[2][r] += a2.x * w.x + a2.y * w.y + a2.z * w.z + a2.w * w.w;
            acc[3][r] += a3.x * w.x + a3.y * w.y + a3.z * w.z + a3.w * w.w;
        }
    }

    // ------- wave-reduce + broadcast to SGPRs -----------------------------
    float ims[4][8];
    #pragma unroll
    for (int m = 0; m < 4; ++m)
        #pragma unroll
        for (int r = 0; r < 8; ++r) {
            float v = acc[m][r];
            v += __shfl_down(v, 32, 64);
            v += __shfl_down(v, 16, 64);
            v += __shfl_down(v, 8, 64);
            v += __shfl_down(v, 4, 64);
            v += __shfl_down(v, 2, 64);
            v += __shfl_down(v, 1, 64);
            ims[m][r] = __int_as_float(__builtin_amdgcn_readfirstlane(
                __float_as_int(v * 4.0f)));           // SCALING folded
        }

    // ------- phase 2: out[m][og] = ims[m] . wBt[.][og] --------------------
    const float4* __restrict__ wt = (const float4*)wBt;   // [8][1024]
    float4* __restrict__ o0 = (float4*)(out + row0 * 4096);

    #pragma unroll 1
    for (int k = 0; k < 16; ++k) {
        const int og = k * 64 + lane;                     // coalesced
        float4 w[8];
        #pragma unroll
        for (int r = 0; r < 8; ++r) w[r] = wt[r * 1024 + og];

        #pragma unroll
        for (int m = 0; m < 4; ++m) {
            float4 s;
            s.x = ims[m][0] * w[0].x + ims[m][1] * w[1].x + ims[m][2] * w[2].x
                + ims[m][3] * w[3].x + ims[m][4] * w[4].x + ims[m][5] * w[5].x
                + ims[m][6] * w[6].x + ims[m][7] * w[7].x;
            s.y = ims[m][0] * w[0].y + ims[m][1] * w[1].y + ims[m][2] * w[2].y
                + ims[m][3] * w[3].y + ims[m][4] * w[4].y + ims[m][5] * w[5].y
                + ims[m][6] * w[6].y + ims[m][7] * w[7].y;
            s.z = ims[m][0] * w[0].z + ims[m][1] * w[1].z + ims[m][2] * w[2].z
                + ims[m][3] * w[3].z + ims[m][4] * w[4].z + ims[m][5] * w[5].z
                + ims[m][6] * w[6].z + ims[m][7] * w[7].z;
            s.w = ims[m][0] * w[0].w + ims[m][1] * w[1].w + ims[m][2] * w[2].w
                + ims[m][3] * w[3].w + ims[m][4] * w[4].w + ims[m][5] * w[5].w
                + ims[m][6] * w[6].w + ims[m][7] * w[7].w;
            o0[m * 1024 + og] = s;                        // coalesced
        }
    }
}

extern "C" void kernel_launch(void* const* d_in, const int* in_sizes, int n_in,
                              void* d_out, int out_size, void* d_ws, size_t ws_size,
                              hipStream_t stream) {
    const float* x        = (const float*)d_in[0];
    const int*   codes_A  = (const int*)d_in[1];
    const float* absmax_A = (const float*)d_in[2];
    const int*   codes_B  = (const int*)d_in[3];
    const float* absmax_B = (const float*)d_in[4];
    float* out = (float*)d_out;

    constexpr int NW = 8 * 4096;                 // elements per factor
    float* wA  = (float*)d_ws;                   // 128 KB
    float* wBt = (float*)d_ws + NW;              // 128 KB (transposed)

    nf4_dequant_kernel<<<(NW + 255) / 256, 256, 0, stream>>>(
        codes_A, absmax_A, codes_B, absmax_B, wA, wBt, NW);

    lora_fused_kernel<<<512, 256, 0, stream>>>(x, wA, wBt, out);
}